// Round 3
// baseline (434.581 us; speedup 1.0000x reference)
//
#include <hip/hip_runtime.h>
#include <stdint.h>

typedef __attribute__((ext_vector_type(8))) short short8;
typedef __attribute__((ext_vector_type(4))) float floatx4;

__device__ inline unsigned short f2bf(float f){
  union { float fv; unsigned int u; } v; v.fv = f;
  unsigned int u = v.u;
  unsigned int r = ((u >> 16) & 1u) + 0x7FFFu;
  return (unsigned short)((u + r) >> 16);
}

// async global->LDS, 16B per lane, dest = wave-uniform base + lane*16
__device__ __forceinline__ void async16(const void* g, void* l){
  __builtin_amdgcn_global_load_lds(
      (const __attribute__((address_space(1))) unsigned int*)g,
      (__attribute__((address_space(3))) unsigned int*)l, 16, 0, 0);
}

// ---------------- weight prep ----------------
// w_s1 [192][3][7][7] -> w1p[o][k], k = (c*7+ky)*8 + kx (kx padded to 8), K'=192
__global__ void prep_w1(const float* __restrict__ w, unsigned short* __restrict__ w1p){
  int i = blockIdx.x*256 + threadIdx.x;
  if (i >= 192*192) return;
  int k = i % 192, o = i / 192;
  int cc = k >> 3, kx = k & 7;
  unsigned short v = 0;
  if (cc < 21 && kx < 7){
    int c = cc / 7, ky = cc % 7;
    v = f2bf(w[(o*3 + c)*49 + ky*7 + kx]);
  }
  w1p[i] = v;
}
// w_s2 [192][192][7][7] -> w2p[o][(ky*7+kx)*192 + c]  (B^T rows, K=9408)
__global__ void prep_w2(const float* __restrict__ w, unsigned short* __restrict__ w2p){
  int i = blockIdx.x*256 + threadIdx.x;
  if (i >= 192*9408) return;
  int k = i % 9408, o = i / 9408;
  int g = k / 192, c = k % 192;
  int ky = g / 7, kx = g % 7;
  w2p[i] = f2bf(w[((o*192 + c)*7 + ky)*7 + kx]);
}
// w_p [768][960][3][3] -> w3p[o][(ky*3+kx)*960 + c]  (B^T rows, K=8640)
__global__ void prep_w3(const float* __restrict__ w, unsigned short* __restrict__ w3p){
  int i = blockIdx.x*256 + threadIdx.x;
  if (i >= 768*8640) return;
  int k = i % 8640, o = i / 8640;
  int g = k / 960, c = k % 960;
  int ky = g / 3, kx = g % 3;
  w3p[i] = f2bf(w[((o*960 + c)*3 + ky)*3 + kx]);
}
__global__ void prep_zp(unsigned int* __restrict__ zp){
  zp[threadIdx.x] = 0u;  // 256 B zero page
}

// ---------------- pad+im2col-kx: x -> xh2[b][c][iy(230)][ox(56)][kx(8)] bf16 ----------------
// xh2[...][ox][kx] = x[iy-3][4*ox-3+kx] (zero outside). Every 8-elem chunk is 16B aligned.
__global__ void pad_x2(const float* __restrict__ x, unsigned short* __restrict__ xh2){
  int idx = blockIdx.x*256 + threadIdx.x;
  if (idx >= 64*3*230*56*8) return;
  int kx = idx & 7; int t = idx >> 3;
  int ox = t % 56;  t /= 56;
  int iy = t % 230; t /= 230;      // t = b*3 + c
  int row = iy - 3;
  int col = 4*ox - 3 + kx;
  unsigned short v = 0;
  if (row >= 0 && row < 224 && col >= 0 && col < 224)
    v = f2bf(x[((size_t)t*224 + row)*224 + col]);
  xh2[idx] = v;
}

// ---------------- wavelet: per 16x16 block 2D WHT / 16 ----------------
__global__ void wavelet_kernel(const float* __restrict__ x, unsigned short* __restrict__ feat){
  int blk = blockIdx.x;
  int j = blk % 14; blk /= 14;
  int i = blk % 14; blk /= 14;
  int c = blk % 3;  int b = blk / 3;
  int t = threadIdx.x;
  int u = t >> 4, v = t & 15;
  float val = x[((size_t)(b*3 + c)*224 + (i*16 + u))*224 + (j*16 + v)];
  #pragma unroll
  for (int bit = 1; bit < 64; bit <<= 1){
    float p = __shfl_xor(val, bit);
    val = (t & bit) ? (p - val) : (val + p);
  }
  __shared__ float s[256];
  #pragma unroll
  for (int bit = 64; bit < 256; bit <<= 1){
    s[t] = val; __syncthreads();
    float p = s[t ^ bit]; __syncthreads();
    val = (t & bit) ? (p - val) : (val + p);
  }
  s[t] = val; __syncthreads();
  int k = t;
  int d1 = (k>>6)&3, d2 = (k>>4)&3, d3 = (k>>2)&3, d4 = k&3;
  int mr = (d1>>1) | ((d2>>1)<<1) | ((d3>>1)<<2) | ((d4>>1)<<3);
  int mc = (d1&1)  | ((d2&1)<<1)  | ((d3&1)<<2)  | ((d4&1)<<3);
  float outv = s[mr*16 + mc] * 0.0625f;
  feat[((size_t)((b*14 + i)*14 + j))*960 + (k*3 + c)] = f2bf(outv);
}

// ---------------- conv1: dbuf glds MFMA GEMM, BM=128 BN=64 K=192 (3 iters) ----------------
__global__ __launch_bounds__(256) void conv1_gemm(const unsigned short* __restrict__ xh2,
                                                  const unsigned short* __restrict__ w1p,
                                                  const float* __restrict__ b1,
                                                  unsigned short* __restrict__ sp1){
  __shared__ unsigned short As[2][128*64], Bs[2][64*64];
  int m0 = blockIdx.x*128, n0 = blockIdx.y*64;
  int tid = threadIdx.x, wave = tid >> 6, lane = tid & 63;
  int l16 = lane & 15, quad = lane >> 4;
  int wy = wave >> 1, wx = wave & 1;
  int r8 = lane >> 3, kb = (lane & 7) ^ r8;

  int Abase[4];
  #pragma unroll
  for (int j = 0; j < 4; j++){
    int row = wave*32 + j*8 + r8;
    int m = m0 + row;
    int ox = m % 56; int t = m / 56; int oy = t % 56; int b = t / 56;
    Abase[j] = (b*690 + 4*oy)*448 + ox*8;  // ((b*3+0)*230 + 4*oy)*56*8 + ox*8
  }
  const unsigned short* pB0 = w1p + (n0 + wave*16 + r8)*192 + kb*8;
  const unsigned short* pB1 = pB0 + 8*192;

  int sw = l16 & 7;
  int xo0 = ((quad    ) ^ sw)*8;
  int xo1 = ((quad + 4) ^ sw)*8;
  int aoff[4];
  #pragma unroll
  for (int mt = 0; mt < 4; mt++) aoff[mt] = (wy*64 + mt*16 + l16)*64;
  int boff0 = (wx*32 + l16)*64, boff1 = boff0 + 16*64;

  floatx4 acc[4][2];
  #pragma unroll
  for (int mt = 0; mt < 4; mt++)
    #pragma unroll
    for (int nt = 0; nt < 2; nt++) acc[mt][nt] = (floatx4){0.f,0.f,0.f,0.f};

  auto stage = [&](int i, int buf){
    int cc = i*8 + kb;
    int c = (cc*147) >> 10;          // cc/7 for cc<24
    int ky = cc - 7*c;
    int koff = (c*230 + ky)*448;
    #pragma unroll
    for (int j = 0; j < 4; j++)
      async16(xh2 + Abase[j] + koff, (void*)&As[buf][(wave*32 + j*8)*64]);
    async16(pB0 + i*64, (void*)&Bs[buf][(wave*16    )*64]);
    async16(pB1 + i*64, (void*)&Bs[buf][(wave*16 + 8)*64]);
  };

  stage(0, 0);
  __syncthreads();
  #pragma unroll
  for (int i = 0; i < 3; i++){
    int buf = i & 1;
    if (i < 2) stage(i+1, buf ^ 1);
    #pragma unroll
    for (int ks = 0; ks < 2; ks++){
      int xo = ks ? xo1 : xo0;
      short8 b0 = *(const short8*)&Bs[buf][boff0 + xo];
      short8 b1 = *(const short8*)&Bs[buf][boff1 + xo];
      #pragma unroll
      for (int mt = 0; mt < 4; mt++){
        short8 a = *(const short8*)&As[buf][aoff[mt] + xo];
        acc[mt][0] = __builtin_amdgcn_mfma_f32_16x16x32_bf16(a, b0, acc[mt][0], 0, 0, 0);
        acc[mt][1] = __builtin_amdgcn_mfma_f32_16x16x32_bf16(a, b1, acc[mt][1], 0, 0, 0);
      }
    }
    __syncthreads();
  }

  #pragma unroll
  for (int mt = 0; mt < 4; mt++){
    #pragma unroll
    for (int rg = 0; rg < 4; rg++){
      int row = wy*64 + mt*16 + quad*4 + rg;
      size_t ob = (size_t)(m0 + row)*192;
      #pragma unroll
      for (int nt = 0; nt < 2; nt++){
        int nn = n0 + wx*32 + nt*16 + l16;
        sp1[ob + nn] = f2bf(acc[mt][nt][rg] + b1[nn]);
      }
    }
  }
}

// ---------------- conv2/conv3: dbuf glds implicit-GEMM, 64x64 tile ----------------
template<int MODE>
__global__ __launch_bounds__(256) void conv_gemm(const unsigned short* __restrict__ Ain,
                                                 const unsigned short* __restrict__ Bt,
                                                 const float* __restrict__ bias,
                                                 const float* __restrict__ pos,
                                                 const unsigned short* __restrict__ zp,
                                                 void* __restrict__ outp){
  constexpr int OH  = (MODE==2) ? 14 : 7;
  constexpr int OW  = OH;
  constexpr int IH  = (MODE==2) ? 56 : 14;
  constexpr int IW  = IH;
  constexpr int Cin = (MODE==2) ? 192 : 960;
  constexpr int KW  = (MODE==2) ? 7 : 3;
  constexpr int S   = (MODE==2) ? 4 : 2;
  constexpr int P   = (MODE==2) ? 3 : 1;
  constexpr int K   = (MODE==2) ? 9408 : 8640;
  constexpr int NIT = K/64;
  constexpr int MTI = (MODE==2) ? 196 : 49;
  constexpr int GRP = (MODE==2) ? 24 : 96;

  int id = blockIdx.x;
  int g = id / GRP, rem = id % GRP;
  int mtile = g*8 + (rem & 7), ntile = rem >> 3;
  if (mtile >= MTI) return;
  int m0 = mtile*64, n0 = ntile*64;

  __shared__ unsigned short As[2][64*64], Bs[2][64*64];
  int tid = threadIdx.x, wave = tid >> 6, lane = tid & 63;
  int l16 = lane & 15, quad = lane >> 4;
  int wy = wave >> 1, wx = wave & 1;

  int r8 = lane >> 3, kb = (lane & 7) ^ r8;
  int rA0 = wave*16 + r8, rA1 = rA0 + 8;

  int m_0 = m0 + rA0;
  int ox0 = m_0 % OW; int t0 = m_0 / OW; int oy0 = t0 % OH; int bb0 = t0 / OH;
  int iyb0 = S*oy0 - P, ixb0 = S*ox0 - P;
  int abase0 = ((bb0*IH + iyb0)*IW + ixb0)*Cin + kb*8;
  int m_1 = m0 + rA1;
  int ox1 = m_1 % OW; int t1 = m_1 / OW; int oy1 = t1 % OH; int bb1 = t1 / OH;
  int iyb1 = S*oy1 - P, ixb1 = S*ox1 - P;
  int abase1 = ((bb1*IH + iyb1)*IW + ixb1)*Cin + kb*8;

  const unsigned short* pB0 = Bt + (size_t)(n0 + rA0)*K + kb*8;
  const unsigned short* pB1 = Bt + (size_t)(n0 + rA1)*K + kb*8;

  int sw = l16 & 7;
  int xo0 = ((quad    ) ^ sw)*8;
  int xo1 = ((quad + 4) ^ sw)*8;
  int aoff0 = (wy*32      + l16)*64;
  int aoff1 = (wy*32 + 16 + l16)*64;
  int boff0 = (wx*32      + l16)*64;
  int boff1 = (wx*32 + 16 + l16)*64;

  floatx4 acc[2][2];
  #pragma unroll
  for (int a = 0; a < 2; a++)
    #pragma unroll
    for (int bq = 0; bq < 2; bq++) acc[a][bq] = (floatx4){0.f,0.f,0.f,0.f};

  int c0 = 0, ky = 0, kx = 0, k0n = 0;

  auto stage = [&](int buf){
    int koff = (ky*IW + kx)*Cin + c0;
    int iy0 = iyb0 + ky, ix0 = ixb0 + kx;
    int iy1 = iyb1 + ky, ix1 = ixb1 + kx;
    const unsigned short* pa0 = ((unsigned)iy0 < (unsigned)IH && (unsigned)ix0 < (unsigned)IW)
                                ? (Ain + (abase0 + koff)) : zp;
    const unsigned short* pa1 = ((unsigned)iy1 < (unsigned)IH && (unsigned)ix1 < (unsigned)IW)
                                ? (Ain + (abase1 + koff)) : zp;
    async16(pa0, (void*)&As[buf][(wave*16    )*64]);
    async16(pa1, (void*)&As[buf][(wave*16 + 8)*64]);
    async16(pB0 + k0n, (void*)&Bs[buf][(wave*16    )*64]);
    async16(pB1 + k0n, (void*)&Bs[buf][(wave*16 + 8)*64]);
    k0n += 64;
    c0 += 64;
    if (c0 == Cin){ c0 = 0; kx++; if (kx == KW){ kx = 0; ky++; } }
  };

  stage(0);
  __syncthreads();
  for (int i = 0; i < NIT; i++){
    int buf = i & 1;
    if (i + 1 < NIT) stage(buf ^ 1);
    #pragma unroll
    for (int ks = 0; ks < 2; ks++){
      int xo = ks ? xo1 : xo0;
      short8 a0 = *(const short8*)&As[buf][aoff0 + xo];
      short8 a1 = *(const short8*)&As[buf][aoff1 + xo];
      short8 b0 = *(const short8*)&Bs[buf][boff0 + xo];
      short8 b1 = *(const short8*)&Bs[buf][boff1 + xo];
      acc[0][0] = __builtin_amdgcn_mfma_f32_16x16x32_bf16(a0, b0, acc[0][0], 0, 0, 0);
      acc[0][1] = __builtin_amdgcn_mfma_f32_16x16x32_bf16(a0, b1, acc[0][1], 0, 0, 0);
      acc[1][0] = __builtin_amdgcn_mfma_f32_16x16x32_bf16(a1, b0, acc[1][0], 0, 0, 0);
      acc[1][1] = __builtin_amdgcn_mfma_f32_16x16x32_bf16(a1, b1, acc[1][1], 0, 0, 0);
    }
    __syncthreads();
  }

  #pragma unroll
  for (int mt = 0; mt < 2; mt++){
    #pragma unroll
    for (int rg = 0; rg < 4; rg++){
      int row = wy*32 + mt*16 + quad*4 + rg;
      int mm = m0 + row;
      #pragma unroll
      for (int nt = 0; nt < 2; nt++){
        int nn = n0 + wx*32 + nt*16 + l16;
        float v = acc[mt][nt][rg] + bias[nn];
        if (MODE == 2){
          ((unsigned short*)outp)[(size_t)mm*960 + 768 + nn] = f2bf(v);
        } else {
          int b2 = mm / 49;
          int tt = mm - b2*49;
          v += pos[(size_t)(1 + tt)*768 + nn];
          ((float*)outp)[((size_t)(mm + b2 + 1))*768 + nn] = v;
        }
      }
    }
  }
}

// ---------------- cls row ----------------
__global__ void cls_kernel(const float* __restrict__ cls, const float* __restrict__ pos,
                           float* __restrict__ out){
  int i = blockIdx.x*256 + threadIdx.x;
  if (i >= 64*768) return;
  int e = i % 768, b = i / 768;
  out[(size_t)(b*50)*768 + e] = cls[e] + pos[e];
}

extern "C" void kernel_launch(void* const* d_in, const int* in_sizes, int n_in,
                              void* d_out, int out_size, void* d_ws, size_t ws_size,
                              hipStream_t stream){
  (void)in_sizes; (void)n_in; (void)out_size;
  const float* x    = (const float*)d_in[0];
  const float* w_s1 = (const float*)d_in[1];
  const float* b_s1 = (const float*)d_in[2];
  const float* w_s2 = (const float*)d_in[3];
  const float* b_s2 = (const float*)d_in[4];
  const float* w_p  = (const float*)d_in[5];
  const float* b_p  = (const float*)d_in[6];
  const float* cls  = (const float*)d_in[7];
  const float* pos  = (const float*)d_in[8];
  float* out = (float*)d_out;

  char* ws = (char*)d_ws;
  // ws layout (bytes):
  //   w1p  bf16 [192][192]              @ 0           (73,728)
  //   sp1  bf16 NHWC [64][56][56][192]  @ 131,072     (77,070,336) end 77,201,408
  //   zp   256 B zeros                  @ 77,201,408
  //   w2p  bf16 [192][9408]             @ 77,266,944  (3,612,672)  end 80,879,616
  //   w3p  bf16 [768][8640]             @ 80,879,616  (13,271,040) end 94,150,656
  //   feat bf16 NHWC [64][14][14][960]  @ 94,150,656  (24,084,480) end 118,235,136
  //   xh2  bf16 [64][3][230][56][8] ALIASES w2p..feat (38,633,472, end 115,900,416)
  //   order: prep_w1 -> pad_x2(xh2) -> conv1(xh2->sp1) -> prep_w2/w3 (xh2 dead)
  //          -> wavelet(feat) -> conv2(sp1->feat) -> conv3(feat->out)
  if (ws_size < 118235136u) return;
  unsigned short* w1p  = (unsigned short*)(ws + 0);
  unsigned short* sp1  = (unsigned short*)(ws + 131072);
  unsigned short* zp   = (unsigned short*)(ws + 77201408u);
  unsigned short* w2p  = (unsigned short*)(ws + 77266944u);
  unsigned short* w3p  = (unsigned short*)(ws + 80879616u);
  unsigned short* feat = (unsigned short*)(ws + 94150656u);
  unsigned short* xh2  = (unsigned short*)(ws + 77266944u);

  prep_w1<<<(192*192 + 255)/256, 256, 0, stream>>>(w_s1, w1p);
  pad_x2<<<(64*3*230*56*8)/256, 256, 0, stream>>>(x, xh2);
  conv1_gemm<<<dim3(1568, 3), 256, 0, stream>>>(xh2, w1p, b_s1, sp1);
  prep_w2<<<(192*9408 + 255)/256, 256, 0, stream>>>(w_s2, w2p);
  prep_w3<<<(768*8640 + 255)/256, 256, 0, stream>>>(w_p, w3p);
  prep_zp<<<1, 64, 0, stream>>>((unsigned int*)zp);
  wavelet_kernel<<<64*3*14*14, 256, 0, stream>>>(x, feat);
  conv_gemm<2><<<600, 256, 0, stream>>>(sp1, w2p, b_s2, nullptr, zp, (void*)feat);
  conv_gemm<3><<<672, 256, 0, stream>>>(feat, w3p, b_p, pos, zp, (void*)out);
  cls_kernel<<<(64*768 + 255)/256, 256, 0, stream>>>(cls, pos, out);
}

// Round 5
// 425.635 us; speedup vs baseline: 1.0210x; 1.0210x over previous
//
#include <hip/hip_runtime.h>
#include <stdint.h>

typedef __attribute__((ext_vector_type(8))) short short8;
typedef __attribute__((ext_vector_type(4))) float floatx4;

__device__ inline unsigned short f2bf(float f){
  union { float fv; unsigned int u; } v; v.fv = f;
  unsigned int u = v.u;
  unsigned int r = ((u >> 16) & 1u) + 0x7FFFu;
  return (unsigned short)((u + r) >> 16);
}

// async global->LDS, 16B per lane, dest = wave-uniform base + lane*16
__device__ __forceinline__ void async16(const void* g, void* l){
  __builtin_amdgcn_global_load_lds(
      (const __attribute__((address_space(1))) unsigned int*)g,
      (__attribute__((address_space(3))) unsigned int*)l, 16, 0, 0);
}

// s_waitcnt vmcnt(N) with memory clobber (pins glds/ds ops), then a proper
// convergent barrier, then another compiler fence so LDS reads can't hoist
// above the barrier. __syncthreads would drain vmcnt(0) — defeats the pipeline.
#define PBAR(N) do {                                              \
    asm volatile("s_waitcnt vmcnt(" #N ")" ::: "memory");          \
    __builtin_amdgcn_s_barrier();                                  \
    asm volatile("" ::: "memory");                                 \
  } while (0)

// ---------------- weight prep ----------------
__global__ void prep_w1(const float* __restrict__ w, unsigned short* __restrict__ w1p){
  int i = blockIdx.x*256 + threadIdx.x;
  if (i >= 192*192) return;
  int k = i % 192, o = i / 192;
  int cc = k >> 3, kx = k & 7;
  unsigned short v = 0;
  if (cc < 21 && kx < 7){
    int c = cc / 7, ky = cc % 7;
    v = f2bf(w[(o*3 + c)*49 + ky*7 + kx]);
  }
  w1p[i] = v;
}
__global__ void prep_w2(const float* __restrict__ w, unsigned short* __restrict__ w2p){
  int i = blockIdx.x*256 + threadIdx.x;
  if (i >= 192*9408) return;
  int k = i % 9408, o = i / 9408;
  int g = k / 192, c = k % 192;
  int ky = g / 7, kx = g % 7;
  w2p[i] = f2bf(w[((o*192 + c)*7 + ky)*7 + kx]);
}
__global__ void prep_w3(const float* __restrict__ w, unsigned short* __restrict__ w3p){
  int i = blockIdx.x*256 + threadIdx.x;
  if (i >= 768*8640) return;
  int k = i % 8640, o = i / 8640;
  int g = k / 960, c = k % 960;
  int ky = g / 3, kx = g % 3;
  w3p[i] = f2bf(w[((o*960 + c)*3 + ky)*3 + kx]);
}
__global__ void prep_zp(unsigned int* __restrict__ zp){
  zp[threadIdx.x] = 0u;  // 256 B zero page
}

// ---------------- pad+im2col-kx: x -> xh2[b][c][iy(230)][ox(56)][kx(8)] bf16 ----------------
__global__ void pad_x2(const float* __restrict__ x, unsigned short* __restrict__ xh2){
  int idx = blockIdx.x*256 + threadIdx.x;
  if (idx >= 64*3*230*56*8) return;
  int kx = idx & 7; int t = idx >> 3;
  int ox = t % 56;  t /= 56;
  int iy = t % 230; t /= 230;      // t = b*3 + c
  int row = iy - 3;
  int col = 4*ox - 3 + kx;
  unsigned short v = 0;
  if (row >= 0 && row < 224 && col >= 0 && col < 224)
    v = f2bf(x[((size_t)t*224 + row)*224 + col]);
  xh2[idx] = v;
}

// ---------------- wavelet: per 16x16 block 2D WHT / 16 ----------------
__global__ void wavelet_kernel(const float* __restrict__ x, unsigned short* __restrict__ feat){
  int blk = blockIdx.x;
  int j = blk % 14; blk /= 14;
  int i = blk % 14; blk /= 14;
  int c = blk % 3;  int b = blk / 3;
  int t = threadIdx.x;
  int u = t >> 4, v = t & 15;
  float val = x[((size_t)(b*3 + c)*224 + (i*16 + u))*224 + (j*16 + v)];
  #pragma unroll
  for (int bit = 1; bit < 64; bit <<= 1){
    float p = __shfl_xor(val, bit);
    val = (t & bit) ? (p - val) : (val + p);
  }
  __shared__ float s[256];
  #pragma unroll
  for (int bit = 64; bit < 256; bit <<= 1){
    s[t] = val; __syncthreads();
    float p = s[t ^ bit]; __syncthreads();
    val = (t & bit) ? (p - val) : (val + p);
  }
  s[t] = val; __syncthreads();
  int k = t;
  int d1 = (k>>6)&3, d2 = (k>>4)&3, d3 = (k>>2)&3, d4 = k&3;
  int mr = (d1>>1) | ((d2>>1)<<1) | ((d3>>1)<<2) | ((d4>>1)<<3);
  int mc = (d1&1)  | ((d2&1)<<1)  | ((d3&1)<<2)  | ((d4&1)<<3);
  float outv = s[mr*16 + mc] * 0.0625f;
  feat[((size_t)((b*14 + i)*14 + j))*960 + (k*3 + c)] = f2bf(outv);
}

// ---------------- conv1: dbuf glds MFMA GEMM, BM=128 BN=64 K=192 (3 iters) ----------------
__global__ __launch_bounds__(256) void conv1_gemm(const unsigned short* __restrict__ xh2,
                                                  const unsigned short* __restrict__ w1p,
                                                  const float* __restrict__ b1,
                                                  unsigned short* __restrict__ sp1){
  __shared__ unsigned short As[2][128*64], Bs[2][64*64];
  int m0 = blockIdx.x*128, n0 = blockIdx.y*64;
  int tid = threadIdx.x, wave = tid >> 6, lane = tid & 63;
  int l16 = lane & 15, quad = lane >> 4;
  int wy = wave >> 1, wx = wave & 1;
  int r8 = lane >> 3, kb = (lane & 7) ^ r8;

  int Abase[4];
  #pragma unroll
  for (int j = 0; j < 4; j++){
    int row = wave*32 + j*8 + r8;
    int m = m0 + row;
    int ox = m % 56; int t = m / 56; int oy = t % 56; int b = t / 56;
    Abase[j] = (b*690 + 4*oy)*448 + ox*8;
  }
  const unsigned short* pB0 = w1p + (n0 + wave*16 + r8)*192 + kb*8;
  const unsigned short* pB1 = pB0 + 8*192;

  int sw = l16 & 7;
  int xo0 = ((quad    ) ^ sw)*8;
  int xo1 = ((quad + 4) ^ sw)*8;
  int aoff[4];
  #pragma unroll
  for (int mt = 0; mt < 4; mt++) aoff[mt] = (wy*64 + mt*16 + l16)*64;
  int boff0 = (wx*32 + l16)*64, boff1 = boff0 + 16*64;

  floatx4 acc[4][2];
  #pragma unroll
  for (int mt = 0; mt < 4; mt++)
    #pragma unroll
    for (int nt = 0; nt < 2; nt++) acc[mt][nt] = (floatx4){0.f,0.f,0.f,0.f};

  auto stage = [&](int i, int buf){
    int cc = i*8 + kb;
    int c = (cc*147) >> 10;
    int ky = cc - 7*c;
    int koff = (c*230 + ky)*448;
    #pragma unroll
    for (int j = 0; j < 4; j++)
      async16(xh2 + Abase[j] + koff, (void*)&As[buf][(wave*32 + j*8)*64]);
    async16(pB0 + i*64, (void*)&Bs[buf][(wave*16    )*64]);
    async16(pB1 + i*64, (void*)&Bs[buf][(wave*16 + 8)*64]);
  };

  stage(0, 0);
  __syncthreads();
  #pragma unroll
  for (int i = 0; i < 3; i++){
    int buf = i & 1;
    if (i < 2) stage(i+1, buf ^ 1);
    #pragma unroll
    for (int ks = 0; ks < 2; ks++){
      int xo = ks ? xo1 : xo0;
      short8 b0 = *(const short8*)&Bs[buf][boff0 + xo];
      short8 b1 = *(const short8*)&Bs[buf][boff1 + xo];
      #pragma unroll
      for (int mt = 0; mt < 4; mt++){
        short8 a = *(const short8*)&As[buf][aoff[mt] + xo];
        acc[mt][0] = __builtin_amdgcn_mfma_f32_16x16x32_bf16(a, b0, acc[mt][0], 0, 0, 0);
        acc[mt][1] = __builtin_amdgcn_mfma_f32_16x16x32_bf16(a, b1, acc[mt][1], 0, 0, 0);
      }
    }
    __syncthreads();
  }

  #pragma unroll
  for (int mt = 0; mt < 4; mt++){
    #pragma unroll
    for (int rg = 0; rg < 4; rg++){
      int row = wy*64 + mt*16 + quad*4 + rg;
      size_t ob = (size_t)(m0 + row)*192;
      #pragma unroll
      for (int nt = 0; nt < 2; nt++){
        int nn = n0 + wx*32 + nt*16 + l16;
        sp1[ob + nn] = f2bf(acc[mt][nt][rg] + b1[nn]);
      }
    }
  }
}

// ---------------- conv2/conv3: depth-2 pipelined glds implicit-GEMM, 64x64 tile ----------------
// 3 LDS buffers (48 KB). Steady state: vmcnt(4) at the barrier keeps the newest
// tile's 4 glds in flight; the computed tile was issued 2 iterations earlier.
template<int MODE>
__global__ __launch_bounds__(256) void conv_gemm(const unsigned short* __restrict__ Ain,
                                                 const unsigned short* __restrict__ Bt,
                                                 const float* __restrict__ bias,
                                                 const float* __restrict__ pos,
                                                 const unsigned short* __restrict__ zp,
                                                 void* __restrict__ outp){
  constexpr int OH  = (MODE==2) ? 14 : 7;
  constexpr int OW  = OH;
  constexpr int IH  = (MODE==2) ? 56 : 14;
  constexpr int IW  = IH;
  constexpr int Cin = (MODE==2) ? 192 : 960;
  constexpr int KW  = (MODE==2) ? 7 : 3;
  constexpr int S   = (MODE==2) ? 4 : 2;
  constexpr int P   = (MODE==2) ? 3 : 1;
  constexpr int K   = (MODE==2) ? 9408 : 8640;
  constexpr int NIT = K/64;
  constexpr int MTI = (MODE==2) ? 196 : 49;
  constexpr int GRP = (MODE==2) ? 24 : 96;

  int id = blockIdx.x;
  int g = id / GRP, rem = id % GRP;
  int mtile = g*8 + (rem & 7), ntile = rem >> 3;
  if (mtile >= MTI) return;
  int m0 = mtile*64, n0 = ntile*64;

  __shared__ unsigned short As[3][64*64], Bs[3][64*64];
  int tid = threadIdx.x, wave = tid >> 6, lane = tid & 63;
  int l16 = lane & 15, quad = lane >> 4;
  int wy = wave >> 1, wx = wave & 1;

  int r8 = lane >> 3, kb = (lane & 7) ^ r8;
  int rA0 = wave*16 + r8, rA1 = rA0 + 8;

  int m_0 = m0 + rA0;
  int ox0 = m_0 % OW; int t0 = m_0 / OW; int oy0 = t0 % OH; int bb0 = t0 / OH;
  int iyb0 = S*oy0 - P, ixb0 = S*ox0 - P;
  int abase0 = ((bb0*IH + iyb0)*IW + ixb0)*Cin + kb*8;
  int m_1 = m0 + rA1;
  int ox1 = m_1 % OW; int t1 = m_1 / OW; int oy1 = t1 % OH; int bb1 = t1 / OH;
  int iyb1 = S*oy1 - P, ixb1 = S*ox1 - P;
  int abase1 = ((bb1*IH + iyb1)*IW + ixb1)*Cin + kb*8;

  const unsigned short* pB0 = Bt + (size_t)(n0 + rA0)*K + kb*8;
  const unsigned short* pB1 = Bt + (size_t)(n0 + rA1)*K + kb*8;

  int sw = l16 & 7;
  int xo0 = ((quad    ) ^ sw)*8;
  int xo1 = ((quad + 4) ^ sw)*8;
  int aoff0 = (wy*32      + l16)*64;
  int aoff1 = (wy*32 + 16 + l16)*64;
  int boff0 = (wx*32      + l16)*64;
  int boff1 = (wx*32 + 16 + l16)*64;

  floatx4 acc[2][2];
  #pragma unroll
  for (int a = 0; a < 2; a++)
    #pragma unroll
    for (int bq = 0; bq < 2; bq++) acc[a][bq] = (floatx4){0.f,0.f,0.f,0.f};

  int c0 = 0, ky = 0, kx = 0, k0n = 0;

  auto stage = [&](int buf){
    int koff = (ky*IW + kx)*Cin + c0;
    int iy0 = iyb0 + ky, ix0 = ixb0 + kx;
    int iy1 = iyb1 + ky, ix1 = ixb1 + kx;
    const unsigned short* pa0 = ((unsigned)iy0 < (unsigned)IH && (unsigned)ix0 < (unsigned)IW)
                                ? (Ain + (abase0 + koff)) : zp;
    const unsigned short* pa1 = ((unsigned)iy1 < (unsigned)IH && (unsigned)ix1 < (unsigned)IW)
                                ? (Ain + (abase1 + koff)) : zp;
    async16(pa0, (void*)&As[buf][(wave*16    )*64]);
    async16(pa1, (void*)&As[buf][(wave*16 + 8)*64]);
    async16(pB0 + k0n, (void*)&Bs[buf][(wave*16    )*64]);
    async16(pB1 + k0n, (void*)&Bs[buf][(wave*16 + 8)*64]);
    k0n += 64;
    c0 += 64;
    if (c0 == Cin){ c0 = 0; kx++; if (kx == KW){ kx = 0; ky++; } }
  };

  auto compute = [&](int buf){
    #pragma unroll
    for (int ks = 0; ks < 2; ks++){
      int xo = ks ? xo1 : xo0;
      short8 a0 = *(const short8*)&As[buf][aoff0 + xo];
      short8 a1 = *(const short8*)&As[buf][aoff1 + xo];
      short8 b0 = *(const short8*)&Bs[buf][boff0 + xo];
      short8 b1 = *(const short8*)&Bs[buf][boff1 + xo];
      acc[0][0] = __builtin_amdgcn_mfma_f32_16x16x32_bf16(a0, b0, acc[0][0], 0, 0, 0);
      acc[0][1] = __builtin_amdgcn_mfma_f32_16x16x32_bf16(a0, b1, acc[0][1], 0, 0, 0);
      acc[1][0] = __builtin_amdgcn_mfma_f32_16x16x32_bf16(a1, b0, acc[1][0], 0, 0, 0);
      acc[1][1] = __builtin_amdgcn_mfma_f32_16x16x32_bf16(a1, b1, acc[1][1], 0, 0, 0);
    }
  };

  // depth-2 pipeline over 3 buffers; 8 glds in flight at each barrier.
  // iter i: [vmcnt(4); barrier] -> tile i landed everywhere, tile i+1 in
  // flight -> stage(i+2) (overwrites buf consumed at iter i-1, all waves past
  // barrier) -> compute(i).
  stage(0); stage(1);
  int bc = 0;                       // buf of tile i
  for (int i = 0; i < NIT - 2; i++){
    PBAR(4);
    int bn = bc + 2; if (bn >= 3) bn -= 3;
    stage(bn);
    compute(bc);
    bc = (bc == 2) ? 0 : bc + 1;
  }
  PBAR(4);
  compute(bc);
  bc = (bc == 2) ? 0 : bc + 1;
  PBAR(0);
  compute(bc);

  #pragma unroll
  for (int mt = 0; mt < 2; mt++){
    #pragma unroll
    for (int rg = 0; rg < 4; rg++){
      int row = wy*32 + mt*16 + quad*4 + rg;
      int mm = m0 + row;
      #pragma unroll
      for (int nt = 0; nt < 2; nt++){
        int nn = n0 + wx*32 + nt*16 + l16;
        float v = acc[mt][nt][rg] + bias[nn];
        if (MODE == 2){
          ((unsigned short*)outp)[(size_t)mm*960 + 768 + nn] = f2bf(v);
        } else {
          int b2 = mm / 49;
          int tt = mm - b2*49;
          v += pos[(size_t)(1 + tt)*768 + nn];
          ((float*)outp)[((size_t)(mm + b2 + 1))*768 + nn] = v;
        }
      }
    }
  }
}

// ---------------- cls row ----------------
__global__ void cls_kernel(const float* __restrict__ cls, const float* __restrict__ pos,
                           float* __restrict__ out){
  int i = blockIdx.x*256 + threadIdx.x;
  if (i >= 64*768) return;
  int e = i % 768, b = i / 768;
  out[(size_t)(b*50)*768 + e] = cls[e] + pos[e];
}

extern "C" void kernel_launch(void* const* d_in, const int* in_sizes, int n_in,
                              void* d_out, int out_size, void* d_ws, size_t ws_size,
                              hipStream_t stream){
  (void)in_sizes; (void)n_in; (void)out_size;
  const float* x    = (const float*)d_in[0];
  const float* w_s1 = (const float*)d_in[1];
  const float* b_s1 = (const float*)d_in[2];
  const float* w_s2 = (const float*)d_in[3];
  const float* b_s2 = (const float*)d_in[4];
  const float* w_p  = (const float*)d_in[5];
  const float* b_p  = (const float*)d_in[6];
  const float* cls  = (const float*)d_in[7];
  const float* pos  = (const float*)d_in[8];
  float* out = (float*)d_out;

  char* ws = (char*)d_ws;
  // ws layout: see round-3 notes (unchanged)
  if (ws_size < 118235136u) return;
  unsigned short* w1p  = (unsigned short*)(ws + 0);
  unsigned short* sp1  = (unsigned short*)(ws + 131072);
  unsigned short* zp   = (unsigned short*)(ws + 77201408u);
  unsigned short* w2p  = (unsigned short*)(ws + 77266944u);
  unsigned short* w3p  = (unsigned short*)(ws + 80879616u);
  unsigned short* feat = (unsigned short*)(ws + 94150656u);
  unsigned short* xh2  = (unsigned short*)(ws + 77266944u);

  prep_w1<<<(192*192 + 255)/256, 256, 0, stream>>>(w_s1, w1p);
  pad_x2<<<(64*3*230*56*8)/256, 256, 0, stream>>>(x, xh2);
  conv1_gemm<<<dim3(1568, 3), 256, 0, stream>>>(xh2, w1p, b_s1, sp1);
  prep_w2<<<(192*9408 + 255)/256, 256, 0, stream>>>(w_s2, w2p);
  prep_w3<<<(768*8640 + 255)/256, 256, 0, stream>>>(w_p, w3p);
  prep_zp<<<1, 64, 0, stream>>>((unsigned int*)zp);
  wavelet_kernel<<<64*3*14*14, 256, 0, stream>>>(x, feat);
  conv_gemm<2><<<600, 256, 0, stream>>>(sp1, w2p, b_s2, nullptr, zp, (void*)feat);
  conv_gemm<3><<<672, 256, 0, stream>>>(feat, w3p, b_p, pos, zp, (void*)out);
  cls_kernel<<<(64*768 + 255)/256, 256, 0, stream>>>(cls, pos, out);
}